// Round 2
// baseline (143.914 us; speedup 1.0000x reference)
//
#include <hip/hip_runtime.h>
#include <math.h>

#define NBATCH 64
#define NCP    512
#define CPD    64
#define NF     256
#define WSZ    512
#define SD     128
#define NSAMP  65536
#define TPROP  8   // ||A||~0.13/step -> truncation error ~1e-14 abs, threshold ~1e-8
#define NSLICE 8
#define SLICE_ELEMS 2048

__device__ __forceinline__ bool better(float v1, int i1, float v2, int i2) {
  // value descending, index ascending tie-break (matches jax argmax/top_k)
  return (v1 > v2) || (v1 == v2 && i1 < i2);
}

__device__ __forceinline__ void cswap(float& v1, int& i1, float& v2, int& i2) {
  if (better(v2, i2, v1, i1)) {
    float tv = v1; v1 = v2; v2 = tv;
    int   ti = i1; i1 = i2; i2 = ti;
  }
}

__device__ __forceinline__ void wave_argmax(float& v, int& i) {
#pragma unroll
  for (int off = 32; off > 0; off >>= 1) {
    float ov = __shfl_down(v, off);
    int   oi = __shfl_down(i, off);
    if (better(ov, oi, v, i)) { v = ov; i = oi; }
  }
}

// merge this lane's sorted-desc 8-list with partner lane's (xor off); both keep top-8
__device__ __forceinline__ void xor_merge8(float* m, int* mi, int off) {
  float lb[8]; int ib8[8];
#pragma unroll
  for (int k = 0; k < 8; k++) { lb[k] = __shfl_xor(m[k], off); ib8[k] = __shfl_xor(mi[k], off); }
  float x[8]; int xi[8];
#pragma unroll
  for (int k = 0; k < 8; k++) {   // top half of merged 16 (bitonic)
    const bool ta = better(m[k], mi[k], lb[7 - k], ib8[7 - k]);
    x[k]  = ta ? m[k]  : lb[7 - k];
    xi[k] = ta ? mi[k] : ib8[7 - k];
  }
  // bitonic clean desc: strides 4,2,1
  cswap(x[0], xi[0], x[4], xi[4]); cswap(x[1], xi[1], x[5], xi[5]);
  cswap(x[2], xi[2], x[6], xi[6]); cswap(x[3], xi[3], x[7], xi[7]);
  cswap(x[0], xi[0], x[2], xi[2]); cswap(x[1], xi[1], x[3], xi[3]);
  cswap(x[4], xi[4], x[6], xi[6]); cswap(x[5], xi[5], x[7], xi[7]);
  cswap(x[0], xi[0], x[1], xi[1]); cswap(x[2], xi[2], x[3], xi[3]);
  cswap(x[4], xi[4], x[5], xi[5]); cswap(x[6], xi[6], x[7], xi[7]);
#pragma unroll
  for (int k = 0; k < 8; k++) { m[k] = x[k]; mi[k] = xi[k]; }
}

// ---------------- K1: blocks 0..63 = S-chain + R (longest pole, dispatched first);
//                     blocks 64..575 = (batch, slice) selection; first 256 also do a P2 quarter ----------------
__global__ __launch_bounds__(256) void k_scan(
    const float* __restrict__ cpc, const float* __restrict__ times,
    const float* __restrict__ lookup,
    const float* __restrict__ proj, const float* __restrict__ Amat,
    const float* __restrict__ Bmat, const float* __restrict__ Cmat,
    const float* __restrict__ Dmat,
    float* __restrict__ P2, float* __restrict__ R,
    float* __restrict__ pmax, float* __restrict__ psum,
    float* __restrict__ pcv, int* __restrict__ pci,
    int* __restrict__ pshift) {
  const int t = threadIdx.x;
  const int bid = blockIdx.x;

  // chain-path LDS: all 8 state vectors, [i][j] layout for float4 broadcast reads
  __shared__ __align__(16) float sjall[SD * 8];   // 4 KB
  __shared__ float sb[2][SD];
  __shared__ float sred[256];
  // slice-path LDS (small)
  __shared__ float wred[4];
  __shared__ int   wredi[4];
  __shared__ int   sRow;
  __shared__ float wlv[32];
  __shared__ int   wli[32];
  __shared__ float sSmax;

  if (bid < CPD) {
    // ----- S-chain: s_j = proj_c @ B @ A^j, then R[j,c,:] = s_j @ C (no global S round-trip) -----
    const int c = bid;
    const int d = t & 127, h = t >> 7;

    // A column d, rows [h*64, h*64+64) -> 64 registers, loaded ONCE (coalesced rows).
    // Issued before the B-pass so the ~L2 latency hides under its compute; all 8 serial
    // recurrence steps then run with zero memory latency (pure LDS + FMA).
    float areg[64];
    {
      const float* Ap = Amat + (size_t)(h * 64) * SD + d;
#pragma unroll
      for (int i = 0; i < 64; i++) areg[i] = Ap[(size_t)i * SD];
    }

    {
      // s0 partials: K-split 2, unroll 16 -> 16 loads in flight per batch
      const float* Bp = Bmat + (size_t)(h * 256) * SD + d;
      const float* pv = proj + (size_t)c * WSZ + h * 256;  // wave-uniform addresses
      float acc[16];
#pragma unroll
      for (int k = 0; k < 16; k++) acc[k] = 0.f;
#pragma unroll 2
      for (int kb = 0; kb < 256; kb += 16) {
#pragma unroll
        for (int u = 0; u < 16; u++)
          acc[u] = fmaf(pv[kb + u], Bp[(size_t)(kb + u) * SD], acc[u]);
      }
      float s8 = 0.f;
#pragma unroll
      for (int k = 0; k < 16; k++) s8 += acc[k];
      sred[t] = s8;
    }
    __syncthreads();
    if (t < SD) sb[0][t] = sred[t] + sred[t + 128];
    __syncthreads();

    int cur = 0;
    for (int j = 0; j < TPROP; j++) {
      if (t < SD) sjall[t * 8 + j] = sb[cur][t];
      // next state: K-split 2, A register-resident
      float a0 = 0.f, a1 = 0.f, a2 = 0.f, a3 = 0.f;
      const float* sh = sb[cur] + h * 64;
#pragma unroll
      for (int i = 0; i < 64; i += 4) {
        const float4 sv = *(const float4*)(sh + i);
        a0 = fmaf(sv.x, areg[i + 0], a0);
        a1 = fmaf(sv.y, areg[i + 1], a1);
        a2 = fmaf(sv.z, areg[i + 2], a2);
        a3 = fmaf(sv.w, areg[i + 3], a3);
      }
      sred[t] = (a0 + a1) + (a2 + a3);
      __syncthreads();
      if (t < SD) sb[cur ^ 1][t] = sred[t] + sred[t + 128];
      __syncthreads();
      cur ^= 1;
    }

    // ----- R pass: one sweep over C, 16 accumulators (8 j x 2 column halves) -----
    float r0[8], r1[8];
#pragma unroll
    for (int k = 0; k < 8; k++) { r0[k] = 0.f; r1[k] = 0.f; }
    const float* Cp = Cmat + t;
#pragma unroll 8
    for (int i = 0; i < SD; i++) {
      const float4 sA = *(const float4*)(sjall + i * 8);      // s_{0..3}[i] broadcast
      const float4 sB = *(const float4*)(sjall + i * 8 + 4);  // s_{4..7}[i]
      const float c0 = Cp[(size_t)i * WSZ];
      const float c1 = Cp[(size_t)i * WSZ + 256];
      r0[0] = fmaf(sA.x, c0, r0[0]); r1[0] = fmaf(sA.x, c1, r1[0]);
      r0[1] = fmaf(sA.y, c0, r0[1]); r1[1] = fmaf(sA.y, c1, r1[1]);
      r0[2] = fmaf(sA.z, c0, r0[2]); r1[2] = fmaf(sA.z, c1, r1[2]);
      r0[3] = fmaf(sA.w, c0, r0[3]); r1[3] = fmaf(sA.w, c1, r1[3]);
      r0[4] = fmaf(sB.x, c0, r0[4]); r1[4] = fmaf(sB.x, c1, r1[4]);
      r0[5] = fmaf(sB.y, c0, r0[5]); r1[5] = fmaf(sB.y, c1, r1[5]);
      r0[6] = fmaf(sB.z, c0, r0[6]); r1[6] = fmaf(sB.z, c1, r1[6]);
      r0[7] = fmaf(sB.w, c0, r0[7]); r1[7] = fmaf(sB.w, c1, r1[7]);
    }
#pragma unroll
    for (int j = 0; j < 8; j++) {
      R[((size_t)j * CPD + c) * WSZ + t]       = r0[j];
      R[((size_t)j * CPD + c) * WSZ + t + 256] = r1[j];
    }
    return;
  }

  const int sbid = bid - CPD;
  const int b = sbid >> 3, s = sbid & 7;
  const int lane = t & 63, wv = t >> 6;

  // --- cpc argmax (redundant across the 8 slice blocks; 2 KB, cheap) ---
  {
    float v0 = cpc[b * NCP + t];
    float v1 = cpc[b * NCP + t + 256];
    float bv = v0; int bi = t;
    if (better(v1, t + 256, bv, bi)) { bv = v1; bi = t + 256; }
    wave_argmax(bv, bi);
    if (lane == 0) { wred[wv] = bv; wredi[wv] = bi; }
    __syncthreads();
    if (t == 0) {
      float fv = wred[0]; int fi = wredi[0];
#pragma unroll
      for (int q = 1; q < 4; q++)
        if (better(wred[q], wredi[q], fv, fi)) { fv = wred[q]; fi = wredi[q]; }
      sRow = fi;
    }
    __syncthreads();
  }
  const float* row = lookup + (size_t)sRow * (CPD * NF);
  const float4* row4 = (const float4*)(row + s * SLICE_ELEMS);

  // --- load 8 elements (2 independent float4) ---
  const float4 va = row4[t];
  const float4 vb = row4[t + 256];
  const int gbase = s * SLICE_ELEMS;
  float ev[8] = {va.x, va.y, va.z, va.w, vb.x, vb.y, vb.z, vb.w};
  int   ei[8] = {gbase + t * 4,        gbase + t * 4 + 1,
                 gbase + t * 4 + 2,    gbase + t * 4 + 3,
                 gbase + 1024 + t * 4, gbase + 1024 + t * 4 + 1,
                 gbase + 1024 + t * 4 + 2, gbase + 1024 + t * 4 + 3};

  // --- per-thread sort desc (static bubble network, registers) ---
  float m[8]; int mi[8];
#pragma unroll
  for (int k = 0; k < 8; k++) { m[k] = ev[k]; mi[k] = ei[k]; }
#pragma unroll
  for (int i = 0; i < 7; i++)
#pragma unroll
    for (int j = 0; j < 7 - i; j++) cswap(m[j], mi[j], m[j + 1], mi[j + 1]);

  // --- wave-level merge: 6 shuffle rounds, no barriers, no LDS ---
  xor_merge8(m, mi, 1);  xor_merge8(m, mi, 2);  xor_merge8(m, mi, 4);
  xor_merge8(m, mi, 8);  xor_merge8(m, mi, 16); xor_merge8(m, mi, 32);

  if (lane < 8) { wlv[wv * 8 + lane] = m[lane]; wli[wv * 8 + lane] = mi[lane]; }
  __syncthreads();

  // --- wave 0: bitonic sort-32 of the 4 wave lists via shuffles ---
  if (wv == 0) {
    float v = (lane < 32) ? wlv[lane] : -3.4e38f;
    int   i = (lane < 32) ? wli[lane] : 0x7fffffff;
#pragma unroll
    for (int k = 2; k <= 32; k <<= 1) {
#pragma unroll
      for (int j = k >> 1; j > 0; j >>= 1) {
        const float pv = __shfl_xor(v, j);
        const int   pi = __shfl_xor(i, j);
        const bool keepBetter = (((lane & k) == 0) == ((lane & j) == 0));
        if (keepBetter == better(pv, pi, v, i)) { v = pv; i = pi; }
      }
    }
    if (lane == 0) sSmax = v;
    if (lane < 8) { pcv[b * 64 + s * 8 + lane] = v; pci[b * 64 + s * 8 + lane] = i; }
  }
  __syncthreads();
  const float smax = sSmax;

  // --- partial exp-sum (8 independent exps per thread) ---
  float se = 0.f;
#pragma unroll
  for (int k = 0; k < 8; k++) se += __expf(ev[k] - smax);
#pragma unroll
  for (int off = 32; off > 0; off >>= 1) se += __shfl_down(se, off);
  if (lane == 0) wred[wv] = se;
  __syncthreads();
  if (t == 0) {
    pmax[b * 8 + s] = smax;
    psum[b * 8 + s] = (wred[0] + wred[1]) + (wred[2] + wred[3]);
  }
  __syncthreads();  // protect wred against reuse below

  // --- dirac shift (slice 0 only): argmax over times[b,0,:256] ---
  if (s == 0) {
    float tv = times[b * NF + t]; int ti = t;
    wave_argmax(tv, ti);
    if (lane == 0) { wred[wv] = tv; wredi[wv] = ti; }
    __syncthreads();
    if (t == 0) {
      float fv = wred[0]; int fi = wredi[0];
#pragma unroll
      for (int q = 1; q < 4; q++)
        if (better(wred[q], wredi[q], fv, fi)) { fv = wred[q]; fi = wredi[q]; }
      pshift[b] = fi * (NSAMP / NF);
    }
  }

  // --- P2 quarter-row (first 256 slice blocks): P2[c, q*128 : q*128+128] = proj[c,:] @ D[:, cols] ---
  if (sbid < 256) {
    const int c2 = sbid >> 2, q = sbid & 3;
    const int col = q * 128 + (t & 127);
    const int uh = t >> 7;                      // K-split 2 over u
    const float* pr = proj + (size_t)c2 * WSZ + uh * 256;  // uniform -> scalar loads
    const float* Dp = Dmat + (size_t)(uh * 256) * WSZ + col;
    float a[8];
#pragma unroll
    for (int k = 0; k < 8; k++) a[k] = 0.f;
#pragma unroll 2
    for (int u = 0; u < 256; u += 8) {
#pragma unroll
      for (int v = 0; v < 8; v++)
        a[v] = fmaf(pr[u + v], Dp[(size_t)(u + v) * WSZ], a[v]);
    }
    float acc = 0.f;
#pragma unroll
    for (int k = 0; k < 8; k++) acc += a[k];
    sred[t] = acc;
    __syncthreads();
    if (t < 128) P2[(size_t)c2 * WSZ + q * 128 + t] = sred[t] + sred[t + 128];
  }
}

// ---------------- K2: per-block redundant top-8 combine (1 wave, deterministic) + output assembly ----------------
// 2048 blocks: 32 per batch, each covering 2048 samples (two float4 per thread)
__global__ __launch_bounds__(256) void k_out(
    const float* __restrict__ pmax, const float* __restrict__ psum,
    const float* __restrict__ pcv, const int* __restrict__ pci,
    const int* __restrict__ pshift,
    const float* __restrict__ P2, const float* __restrict__ R,
    float* __restrict__ out) {
  const int b = blockIdx.x >> 5;        // 32 blocks per batch
  const int chunk = blockIdx.x & 31;
  const int t = threadIdx.x;
  __shared__ float lv[8];
  __shared__ int   lc[8];
  __shared__ int   lf[8];

  if (t < 64) {
    // merge 8 slice top-8 lists for batch b (identical in every block of this batch)
    const int sl = t >> 3;
    float M = pmax[b * 8 + sl];
#pragma unroll
    for (int off = 1; off < 64; off <<= 1) M = fmaxf(M, __shfl_xor(M, off));
    float ps = ((t & 7) == 0) ? psum[b * 8 + sl] * __expf(pmax[b * 8 + sl] - M) : 0.f;
#pragma unroll
    for (int off = 1; off < 64; off <<= 1) ps += __shfl_xor(ps, off);
    float cvv = pcv[b * 64 + t]; int cii = pci[b * 64 + t];
    for (int p = 0; p < 8; p++) {
      float v = cvv; int i = cii;
#pragma unroll
      for (int off = 1; off < 64; off <<= 1) {
        float ov = __shfl_xor(v, off); int oi = __shfl_xor(i, off);
        if (better(ov, oi, v, i)) { v = ov; i = oi; }
      }
      if (t == 0) {
        lv[p] = __expf(v - M) / ps;
        lc[p] = i / NF;
        lf[p] = i % NF;
      }
      if (cii == i) cvv = -3.4e38f;
    }
  }
  __syncthreads();

  const int shift = pshift[b];
#pragma unroll 2
  for (int half = 0; half < 2; half++) {
    const int n = chunk * 2048 + half * 1024 + t * 4;  // 4 samples per thread per half
    const int m = n - shift;              // shift is a multiple of 256 -> all 4 samples share frames
    float o[4] = {0.f, 0.f, 0.f, 0.f};
    if (m >= 0) {
      const int f1 = m >> 8;
      const int w1 = m & 255;
      float a[4] = {0.f, 0.f, 0.f, 0.f};
      float g[4] = {0.f, 0.f, 0.f, 0.f};
      const bool hasf2 = (f1 > 0);
#pragma unroll
      for (int k = 0; k < 8; k++) {
        const float v = lv[k];
        const int c = lc[k];
        const int d1 = f1 - lf[k];
        if (d1 >= 0 && d1 < TPROP) {
          const float4 q = *(const float4*)(R + ((size_t)(d1 * CPD + c)) * WSZ + w1);
          a[0] += v * q.x; a[1] += v * q.y; a[2] += v * q.z; a[3] += v * q.w;
        }
        if (d1 == 0) {
          const float4 q = *(const float4*)(P2 + (size_t)c * WSZ + w1);
          a[0] += v * q.x; a[1] += v * q.y; a[2] += v * q.z; a[3] += v * q.w;
        }
        if (hasf2) {
          const int d2 = d1 - 1;
          if (d2 >= 0 && d2 < TPROP) {
            const float4 q = *(const float4*)(R + ((size_t)(d2 * CPD + c)) * WSZ + w1 + 256);
            g[0] += v * q.x; g[1] += v * q.y; g[2] += v * q.z; g[3] += v * q.w;
          }
          if (d2 == 0) {
            const float4 q = *(const float4*)(P2 + (size_t)c * WSZ + w1 + 256);
            g[0] += v * q.x; g[1] += v * q.y; g[2] += v * q.z; g[3] += v * q.w;
          }
        }
      }
      const float k2pi = 6.283185307179586f / (float)WSZ;
#pragma unroll
      for (int i = 0; i < 4; i++) {
        const float cs = __cosf(k2pi * (float)(w1 + i));
        const float wa = 0.5f * (1.f - cs);
        const float wb = 0.5f * (1.f + cs);
        o[i] = wa * a[i] + wb * g[i];
      }
    }
    float4 ov = make_float4(o[0], o[1], o[2], o[3]);
    *(float4*)(out + (size_t)b * NSAMP + n) = ov;
  }
}

extern "C" void kernel_launch(void* const* d_in, const int* in_sizes, int n_in,
                              void* d_out, int out_size, void* d_ws, size_t ws_size,
                              hipStream_t stream) {
  const float* cpc    = (const float*)d_in[0];
  const float* times  = (const float*)d_in[1];
  const float* lookup = (const float*)d_in[2];
  const float* proj   = (const float*)d_in[3];
  const float* Amat   = (const float*)d_in[4];
  const float* Bmat   = (const float*)d_in[5];
  const float* Cmat   = (const float*)d_in[6];
  const float* Dmat   = (const float*)d_in[7];
  float* out = (float*)d_out;

  // ws floats: [1536 reserved] pshift[64] P2[32768] R[262144] [S region unused]
  //            pmax[512] psum[512] pcv[4096] pci[4096]   (layout kept from previous version)
  float* w      = (float*)d_ws;
  int*   pshift = (int*)(w + 1536);
  float* P2     = w + 1600;
  float* R      = P2 + CPD * WSZ;
  float* S_unused = R + (size_t)TPROP * CPD * WSZ;
  float* pmax   = S_unused + (size_t)TPROP * CPD * SD;
  float* psum   = pmax + NBATCH * NSLICE;
  float* pcv    = psum + NBATCH * NSLICE;
  int*   pci    = (int*)(pcv + NBATCH * NSLICE * 8);

  hipLaunchKernelGGL(k_scan, dim3(CPD + NBATCH * NSLICE), dim3(256), 0, stream,
                     cpc, times, lookup, proj, Amat, Bmat, Cmat, Dmat,
                     P2, R, pmax, psum, pcv, pci, pshift);
  hipLaunchKernelGGL(k_out, dim3(NBATCH * 32), dim3(256), 0, stream,
                     pmax, psum, pcv, pci, pshift, P2, R, out);
}

// Round 3
// 126.065 us; speedup vs baseline: 1.1416x; 1.1416x over previous
//
#include <hip/hip_runtime.h>
#include <math.h>

#define NBATCH 64
#define NCP    512
#define CPD    64
#define NF     256
#define WSZ    512
#define SD     128
#define NSAMP  65536
#define TPROP  8   // ||A||~0.13/step -> truncation error ~1e-14 abs, threshold ~1e-8
#define NSLICE 8
#define SLICE_ELEMS 2048

__device__ __forceinline__ bool better(float v1, int i1, float v2, int i2) {
  // value descending, index ascending tie-break (matches jax argmax/top_k)
  return (v1 > v2) || (v1 == v2 && i1 < i2);
}

__device__ __forceinline__ void cswap(float& v1, int& i1, float& v2, int& i2) {
  if (better(v2, i2, v1, i1)) {
    float tv = v1; v1 = v2; v2 = tv;
    int   ti = i1; i1 = i2; i2 = ti;
  }
}

__device__ __forceinline__ void wave_argmax(float& v, int& i) {
#pragma unroll
  for (int off = 32; off > 0; off >>= 1) {
    float ov = __shfl_down(v, off);
    int   oi = __shfl_down(i, off);
    if (better(ov, oi, v, i)) { v = ov; i = oi; }
  }
}

// merge this lane's sorted-desc 8-list with partner lane's (xor off); both keep top-8
__device__ __forceinline__ void xor_merge8(float* m, int* mi, int off) {
  float lb[8]; int ib8[8];
#pragma unroll
  for (int k = 0; k < 8; k++) { lb[k] = __shfl_xor(m[k], off); ib8[k] = __shfl_xor(mi[k], off); }
  float x[8]; int xi[8];
#pragma unroll
  for (int k = 0; k < 8; k++) {   // top half of merged 16 (bitonic)
    const bool ta = better(m[k], mi[k], lb[7 - k], ib8[7 - k]);
    x[k]  = ta ? m[k]  : lb[7 - k];
    xi[k] = ta ? mi[k] : ib8[7 - k];
  }
  // bitonic clean desc: strides 4,2,1
  cswap(x[0], xi[0], x[4], xi[4]); cswap(x[1], xi[1], x[5], xi[5]);
  cswap(x[2], xi[2], x[6], xi[6]); cswap(x[3], xi[3], x[7], xi[7]);
  cswap(x[0], xi[0], x[2], xi[2]); cswap(x[1], xi[1], x[3], xi[3]);
  cswap(x[4], xi[4], x[6], xi[6]); cswap(x[5], xi[5], x[7], xi[7]);
  cswap(x[0], xi[0], x[1], xi[1]); cswap(x[2], xi[2], x[3], xi[3]);
  cswap(x[4], xi[4], x[5], xi[5]); cswap(x[6], xi[6], x[7], xi[7]);
#pragma unroll
  for (int k = 0; k < 8; k++) { m[k] = x[k]; mi[k] = xi[k]; }
}

// ---------------- K1: blocks 0..63 = S-chain + R (longest pole, dispatched first);
//                     blocks 64..575 = (batch, slice) selection; first 256 also do a P2 quarter ----------------
__global__ __launch_bounds__(256) void k_scan(
    const float* __restrict__ cpc, const float* __restrict__ times,
    const float* __restrict__ lookup,
    const float* __restrict__ proj, const float* __restrict__ Amat,
    const float* __restrict__ Bmat, const float* __restrict__ Cmat,
    const float* __restrict__ Dmat,
    float* __restrict__ P2, float* __restrict__ R,
    float* __restrict__ pmax, float* __restrict__ psum,
    float* __restrict__ pcv, int* __restrict__ pci,
    int* __restrict__ pshift) {
  const int t = threadIdx.x;
  const int bid = blockIdx.x;

  // chain-path LDS: all 8 state vectors, [i][j] layout for float4 broadcast reads
  __shared__ __align__(16) float sjall[SD * 8];   // 4 KB
  __shared__ float sb[2][SD];
  __shared__ float sred[256];
  // slice-path LDS (small)
  __shared__ float wred[4];
  __shared__ int   wredi[4];
  __shared__ int   sRow;
  __shared__ float wlv[32];
  __shared__ int   wli[32];
  __shared__ float sSmax;

  if (bid < CPD) {
    // ----- S-chain: s_j = proj_c @ B @ A^j, then R[j,c,:] = s_j @ C (no global S round-trip) -----
    // NOTE: A stays in L2 (64 KB, shared by all 64 chain blocks). A 64-deep per-thread
    // register copy was tried and REGRESSED (compiler held VGPR=60 and rematerialized the
    // loads inside the serial loop -> k_scan 55-66 us vs <44 here). Do not reintroduce.
    const int c = bid;
    const int d = t & 127, h = t >> 7;
    {
      // s0 partials: K-split 2, unroll 16 -> 16 loads in flight per batch
      const float* Bp = Bmat + (size_t)(h * 256) * SD + d;
      const float* pv = proj + (size_t)c * WSZ + h * 256;  // wave-uniform addresses
      float acc[16];
#pragma unroll
      for (int k = 0; k < 16; k++) acc[k] = 0.f;
#pragma unroll 2
      for (int kb = 0; kb < 256; kb += 16) {
#pragma unroll
        for (int u = 0; u < 16; u++)
          acc[u] = fmaf(pv[kb + u], Bp[(size_t)(kb + u) * SD], acc[u]);
      }
      float s8 = 0.f;
#pragma unroll
      for (int k = 0; k < 16; k++) s8 += acc[k];
      sred[t] = s8;
    }
    __syncthreads();
    if (t < SD) sb[0][t] = sred[t] + sred[t + 128];
    __syncthreads();

    int cur = 0;
    for (int j = 0; j < TPROP; j++) {
      if (t < SD) sjall[t * 8 + j] = sb[cur][t];
      // next state: K-split 2 over L2-resident A
      float a0 = 0.f, a1 = 0.f, a2 = 0.f, a3 = 0.f;
      const float* Ah = Amat + (size_t)(h * 64) * SD + d;
      const float* sh = sb[cur] + h * 64;
#pragma unroll
      for (int i = 0; i < 64; i += 4) {
        const float4 sv = *(const float4*)(sh + i);
        a0 = fmaf(sv.x, Ah[(size_t)(i + 0) * SD], a0);
        a1 = fmaf(sv.y, Ah[(size_t)(i + 1) * SD], a1);
        a2 = fmaf(sv.z, Ah[(size_t)(i + 2) * SD], a2);
        a3 = fmaf(sv.w, Ah[(size_t)(i + 3) * SD], a3);
      }
      sred[t] = (a0 + a1) + (a2 + a3);
      __syncthreads();
      if (t < SD) sb[cur ^ 1][t] = sred[t] + sred[t + 128];
      __syncthreads();
      cur ^= 1;
    }

    // ----- R pass: one sweep over C, 16 accumulators (8 j x 2 column halves) -----
    float r0[8], r1[8];
#pragma unroll
    for (int k = 0; k < 8; k++) { r0[k] = 0.f; r1[k] = 0.f; }
    const float* Cp = Cmat + t;
#pragma unroll 4
    for (int i = 0; i < SD; i++) {
      const float4 sA = *(const float4*)(sjall + i * 8);      // s_{0..3}[i] broadcast
      const float4 sB = *(const float4*)(sjall + i * 8 + 4);  // s_{4..7}[i]
      const float c0 = Cp[(size_t)i * WSZ];
      const float c1 = Cp[(size_t)i * WSZ + 256];
      r0[0] = fmaf(sA.x, c0, r0[0]); r1[0] = fmaf(sA.x, c1, r1[0]);
      r0[1] = fmaf(sA.y, c0, r0[1]); r1[1] = fmaf(sA.y, c1, r1[1]);
      r0[2] = fmaf(sA.z, c0, r0[2]); r1[2] = fmaf(sA.z, c1, r1[2]);
      r0[3] = fmaf(sA.w, c0, r0[3]); r1[3] = fmaf(sA.w, c1, r1[3]);
      r0[4] = fmaf(sB.x, c0, r0[4]); r1[4] = fmaf(sB.x, c1, r1[4]);
      r0[5] = fmaf(sB.y, c0, r0[5]); r1[5] = fmaf(sB.y, c1, r1[5]);
      r0[6] = fmaf(sB.z, c0, r0[6]); r1[6] = fmaf(sB.z, c1, r1[6]);
      r0[7] = fmaf(sB.w, c0, r0[7]); r1[7] = fmaf(sB.w, c1, r1[7]);
    }
#pragma unroll
    for (int j = 0; j < 8; j++) {
      R[((size_t)j * CPD + c) * WSZ + t]       = r0[j];
      R[((size_t)j * CPD + c) * WSZ + t + 256] = r1[j];
    }
    return;
  }

  const int sbid = bid - CPD;
  const int b = sbid >> 3, s = sbid & 7;
  const int lane = t & 63, wv = t >> 6;

  // --- cpc argmax (redundant across the 8 slice blocks; 2 KB, cheap) ---
  {
    float v0 = cpc[b * NCP + t];
    float v1 = cpc[b * NCP + t + 256];
    float bv = v0; int bi = t;
    if (better(v1, t + 256, bv, bi)) { bv = v1; bi = t + 256; }
    wave_argmax(bv, bi);
    if (lane == 0) { wred[wv] = bv; wredi[wv] = bi; }
    __syncthreads();
    if (t == 0) {
      float fv = wred[0]; int fi = wredi[0];
#pragma unroll
      for (int q = 1; q < 4; q++)
        if (better(wred[q], wredi[q], fv, fi)) { fv = wred[q]; fi = wredi[q]; }
      sRow = fi;
    }
    __syncthreads();
  }
  const float* row = lookup + (size_t)sRow * (CPD * NF);
  const float4* row4 = (const float4*)(row + s * SLICE_ELEMS);

  // --- load 8 elements (2 independent float4) ---
  const float4 va = row4[t];
  const float4 vb = row4[t + 256];
  const int gbase = s * SLICE_ELEMS;
  float ev[8] = {va.x, va.y, va.z, va.w, vb.x, vb.y, vb.z, vb.w};
  int   ei[8] = {gbase + t * 4,        gbase + t * 4 + 1,
                 gbase + t * 4 + 2,    gbase + t * 4 + 3,
                 gbase + 1024 + t * 4, gbase + 1024 + t * 4 + 1,
                 gbase + 1024 + t * 4 + 2, gbase + 1024 + t * 4 + 3};

  // --- per-thread sort desc (static bubble network, registers) ---
  float m[8]; int mi[8];
#pragma unroll
  for (int k = 0; k < 8; k++) { m[k] = ev[k]; mi[k] = ei[k]; }
#pragma unroll
  for (int i = 0; i < 7; i++)
#pragma unroll
    for (int j = 0; j < 7 - i; j++) cswap(m[j], mi[j], m[j + 1], mi[j + 1]);

  // --- wave-level merge: 6 shuffle rounds, no barriers, no LDS ---
  xor_merge8(m, mi, 1);  xor_merge8(m, mi, 2);  xor_merge8(m, mi, 4);
  xor_merge8(m, mi, 8);  xor_merge8(m, mi, 16); xor_merge8(m, mi, 32);

  if (lane < 8) { wlv[wv * 8 + lane] = m[lane]; wli[wv * 8 + lane] = mi[lane]; }
  __syncthreads();

  // --- wave 0: bitonic sort-32 of the 4 wave lists via shuffles ---
  if (wv == 0) {
    float v = (lane < 32) ? wlv[lane] : -3.4e38f;
    int   i = (lane < 32) ? wli[lane] : 0x7fffffff;
#pragma unroll
    for (int k = 2; k <= 32; k <<= 1) {
#pragma unroll
      for (int j = k >> 1; j > 0; j >>= 1) {
        const float pv = __shfl_xor(v, j);
        const int   pi = __shfl_xor(i, j);
        const bool keepBetter = (((lane & k) == 0) == ((lane & j) == 0));
        if (keepBetter == better(pv, pi, v, i)) { v = pv; i = pi; }
      }
    }
    if (lane == 0) sSmax = v;
    if (lane < 8) { pcv[b * 64 + s * 8 + lane] = v; pci[b * 64 + s * 8 + lane] = i; }
  }
  __syncthreads();
  const float smax = sSmax;

  // --- partial exp-sum (8 independent exps per thread) ---
  float se = 0.f;
#pragma unroll
  for (int k = 0; k < 8; k++) se += __expf(ev[k] - smax);
#pragma unroll
  for (int off = 32; off > 0; off >>= 1) se += __shfl_down(se, off);
  if (lane == 0) wred[wv] = se;
  __syncthreads();
  if (t == 0) {
    pmax[b * 8 + s] = smax;
    psum[b * 8 + s] = (wred[0] + wred[1]) + (wred[2] + wred[3]);
  }
  __syncthreads();  // protect wred against reuse below

  // --- dirac shift (slice 0 only): argmax over times[b,0,:256] ---
  if (s == 0) {
    float tv = times[b * NF + t]; int ti = t;
    wave_argmax(tv, ti);
    if (lane == 0) { wred[wv] = tv; wredi[wv] = ti; }
    __syncthreads();
    if (t == 0) {
      float fv = wred[0]; int fi = wredi[0];
#pragma unroll
      for (int q = 1; q < 4; q++)
        if (better(wred[q], wredi[q], fv, fi)) { fv = wred[q]; fi = wredi[q]; }
      pshift[b] = fi * (NSAMP / NF);
    }
  }

  // --- P2 quarter-row (first 256 slice blocks): P2[c, q*128 : q*128+128] = proj[c,:] @ D[:, cols] ---
  if (sbid < 256) {
    const int c2 = sbid >> 2, q = sbid & 3;
    const int col = q * 128 + (t & 127);
    const int uh = t >> 7;                      // K-split 2 over u
    const float* pr = proj + (size_t)c2 * WSZ + uh * 256;  // uniform -> scalar loads
    const float* Dp = Dmat + (size_t)(uh * 256) * WSZ + col;
    float a[8];
#pragma unroll
    for (int k = 0; k < 8; k++) a[k] = 0.f;
#pragma unroll 2
    for (int u = 0; u < 256; u += 8) {
#pragma unroll
      for (int v = 0; v < 8; v++)
        a[v] = fmaf(pr[u + v], Dp[(size_t)(u + v) * WSZ], a[v]);
    }
    float acc = 0.f;
#pragma unroll
    for (int k = 0; k < 8; k++) acc += a[k];
    sred[t] = acc;
    __syncthreads();
    if (t < 128) P2[(size_t)c2 * WSZ + q * 128 + t] = sred[t] + sred[t + 128];
  }
}

// ---------------- K2: per-block redundant top-8 combine (1 wave, deterministic) + output assembly ----------------
// 2048 blocks: 32 per batch, each covering 2048 samples (two float4 per thread)
__global__ __launch_bounds__(256) void k_out(
    const float* __restrict__ pmax, const float* __restrict__ psum,
    const float* __restrict__ pcv, const int* __restrict__ pci,
    const int* __restrict__ pshift,
    const float* __restrict__ P2, const float* __restrict__ R,
    float* __restrict__ out) {
  const int b = blockIdx.x >> 5;        // 32 blocks per batch
  const int chunk = blockIdx.x & 31;
  const int t = threadIdx.x;
  __shared__ float lv[8];
  __shared__ int   lc[8];
  __shared__ int   lf[8];

  const int shift = pshift[b];          // issue early: latency hides under the combine

  if (t < 64) {
    // merge 8 slice top-8 lists for batch b (identical in every block of this batch)
    const int sl = t >> 3;
    float M = pmax[b * 8 + sl];
#pragma unroll
    for (int off = 1; off < 64; off <<= 1) M = fmaxf(M, __shfl_xor(M, off));
    float ps = ((t & 7) == 0) ? psum[b * 8 + sl] * __expf(pmax[b * 8 + sl] - M) : 0.f;
#pragma unroll
    for (int off = 1; off < 64; off <<= 1) ps += __shfl_xor(ps, off);
    float cvv = pcv[b * 64 + t]; int cii = pci[b * 64 + t];
    for (int p = 0; p < 8; p++) {
      float v = cvv; int i = cii;
#pragma unroll
      for (int off = 1; off < 64; off <<= 1) {
        float ov = __shfl_xor(v, off); int oi = __shfl_xor(i, off);
        if (better(ov, oi, v, i)) { v = ov; i = oi; }
      }
      if (t == 0) {
        lv[p] = __expf(v - M) / ps;
        lc[p] = i / NF;
        lf[p] = i % NF;
      }
      if (cii == i) cvv = -3.4e38f;
    }
  }
  __syncthreads();

#pragma unroll 2
  for (int half = 0; half < 2; half++) {
    const int n = chunk * 2048 + half * 1024 + t * 4;  // 4 samples per thread per half
    const int m = n - shift;              // shift is a multiple of 256 -> all 4 samples share frames
    float o[4] = {0.f, 0.f, 0.f, 0.f};
    if (m >= 0) {
      const int f1 = m >> 8;
      const int w1 = m & 255;
      float a[4] = {0.f, 0.f, 0.f, 0.f};
      float g[4] = {0.f, 0.f, 0.f, 0.f};
      const bool hasf2 = (f1 > 0);
#pragma unroll
      for (int k = 0; k < 8; k++) {
        const float v = lv[k];
        const int c = lc[k];
        const int d1 = f1 - lf[k];
        if (d1 >= 0 && d1 < TPROP) {
          const float4 q = *(const float4*)(R + ((size_t)(d1 * CPD + c)) * WSZ + w1);
          a[0] += v * q.x; a[1] += v * q.y; a[2] += v * q.z; a[3] += v * q.w;
        }
        if (d1 == 0) {
          const float4 q = *(const float4*)(P2 + (size_t)c * WSZ + w1);
          a[0] += v * q.x; a[1] += v * q.y; a[2] += v * q.z; a[3] += v * q.w;
        }
        if (hasf2) {
          const int d2 = d1 - 1;
          if (d2 >= 0 && d2 < TPROP) {
            const float4 q = *(const float4*)(R + ((size_t)(d2 * CPD + c)) * WSZ + w1 + 256);
            g[0] += v * q.x; g[1] += v * q.y; g[2] += v * q.z; g[3] += v * q.w;
          }
          if (d2 == 0) {
            const float4 q = *(const float4*)(P2 + (size_t)c * WSZ + w1 + 256);
            g[0] += v * q.x; g[1] += v * q.y; g[2] += v * q.z; g[3] += v * q.w;
          }
        }
      }
      const float k2pi = 6.283185307179586f / (float)WSZ;
#pragma unroll
      for (int i = 0; i < 4; i++) {
        const float cs = __cosf(k2pi * (float)(w1 + i));
        const float wa = 0.5f * (1.f - cs);
        const float wb = 0.5f * (1.f + cs);
        o[i] = wa * a[i] + wb * g[i];
      }
    }
    float4 ov = make_float4(o[0], o[1], o[2], o[3]);
    *(float4*)(out + (size_t)b * NSAMP + n) = ov;
  }
}

extern "C" void kernel_launch(void* const* d_in, const int* in_sizes, int n_in,
                              void* d_out, int out_size, void* d_ws, size_t ws_size,
                              hipStream_t stream) {
  const float* cpc    = (const float*)d_in[0];
  const float* times  = (const float*)d_in[1];
  const float* lookup = (const float*)d_in[2];
  const float* proj   = (const float*)d_in[3];
  const float* Amat   = (const float*)d_in[4];
  const float* Bmat   = (const float*)d_in[5];
  const float* Cmat   = (const float*)d_in[6];
  const float* Dmat   = (const float*)d_in[7];
  float* out = (float*)d_out;

  // ws floats: [1536 reserved] pshift[64] P2[32768] R[262144] [S region unused]
  //            pmax[512] psum[512] pcv[4096] pci[4096]   (layout kept from previous version)
  float* w      = (float*)d_ws;
  int*   pshift = (int*)(w + 1536);
  float* P2     = w + 1600;
  float* R      = P2 + CPD * WSZ;
  float* S_unused = R + (size_t)TPROP * CPD * WSZ;
  float* pmax   = S_unused + (size_t)TPROP * CPD * SD;
  float* psum   = pmax + NBATCH * NSLICE;
  float* pcv    = psum + NBATCH * NSLICE;
  int*   pci    = (int*)(pcv + NBATCH * NSLICE * 8);

  hipLaunchKernelGGL(k_scan, dim3(CPD + NBATCH * NSLICE), dim3(256), 0, stream,
                     cpc, times, lookup, proj, Amat, Bmat, Cmat, Dmat,
                     P2, R, pmax, psum, pcv, pci, pshift);
  hipLaunchKernelGGL(k_out, dim3(NBATCH * 32), dim3(256), 0, stream,
                     pmax, psum, pcv, pci, pshift, P2, R, out);
}